// Round 1
// baseline (768.027 us; speedup 1.0000x reference)
//
#include <hip/hip_runtime.h>

#define NN 100000
#define NE 1200000
#define NG 8
#define DIM 64

// ---- degree histogram (float counts via atomics) ----
__global__ void degree_kernel(const int* __restrict__ esrc, const int* __restrict__ edst,
                              float* __restrict__ dout, float* __restrict__ din, int E) {
  int i = blockIdx.x * blockDim.x + threadIdx.x;
  int stride = gridDim.x * blockDim.x;
  for (; i < E; i += stride) {
    atomicAdd(&dout[esrc[i]], 1.0f);
    atomicAdd(&din[edst[i]], 1.0f);
  }
}

// ---- in-place deg -> rsqrt(max(deg,1)) ----
__global__ void norm_kernel(float* __restrict__ dout, float* __restrict__ din, int N) {
  int i = blockIdx.x * blockDim.x + threadIdx.x;
  if (i < N) {
    dout[i] = rsqrtf(fmaxf(dout[i], 1.0f));
    din[i] = rsqrtf(fmaxf(din[i], 1.0f));
  }
}

// ---- edge scatter: agg[dst][lane] += x[src][lane] * snorm[src]; one edge per wave ----
__global__ __launch_bounds__(256) void scatter_kernel(
    const float* __restrict__ x, const float* __restrict__ snorm,
    const int* __restrict__ esrc, const int* __restrict__ edst,
    float* __restrict__ agg, int E) {
  int lane = threadIdx.x & 63;
  int wave = (blockIdx.x * blockDim.x + threadIdx.x) >> 6;
  int nwaves = (gridDim.x * blockDim.x) >> 6;
  for (int e = wave; e < E; e += nwaves) {
    int s = esrc[e];
    int d = edst[e];
    float v = x[(size_t)s * DIM + lane] * snorm[s];
    atomicAdd(&agg[(size_t)d * DIM + lane], v);
  }
}

// ---- fused: h[n] = relu((agg[n]*dnorm[n]) @ W + b), in place over agg ----
__global__ __launch_bounds__(256) void node_mlp_kernel(
    float* __restrict__ agg, const float* __restrict__ dnorm,
    const float* __restrict__ W, const float* __restrict__ b, int N) {
  __shared__ float Wl[DIM * DIM];
  __shared__ float bl[DIM];
  for (int t = threadIdx.x; t < DIM * DIM; t += blockDim.x) Wl[t] = W[t];
  if (threadIdx.x < DIM) bl[threadIdx.x] = b[threadIdx.x];
  __syncthreads();
  int lane = threadIdx.x & 63;
  int wid = threadIdx.x >> 6;
  int wavesTotal = (gridDim.x * blockDim.x) >> 6;
  for (int n = blockIdx.x * 4 + wid; n < N; n += wavesTotal) {
    float a = agg[(size_t)n * DIM + lane] * dnorm[n];
    float acc = bl[lane];
#pragma unroll
    for (int k = 0; k < DIM; ++k) {
      // broadcast lane k's activation to all lanes via v_readlane (SGPR)
      float ak = __uint_as_float(__builtin_amdgcn_readlane(__float_as_uint(a), k));
      acc = fmaf(ak, Wl[k * DIM + lane], acc);
    }
    agg[(size_t)n * DIM + lane] = fmaxf(acc, 0.0f);
  }
}

// ---- per-graph sum + count (LDS-hierarchical) ----
__global__ __launch_bounds__(256) void pool_kernel(
    const float* __restrict__ h, const int* __restrict__ gid,
    float* __restrict__ gsum, float* __restrict__ gcnt, int N) {
  __shared__ float lsum[NG * DIM];
  __shared__ float lcnt[NG];
  for (int t = threadIdx.x; t < NG * DIM; t += blockDim.x) lsum[t] = 0.0f;
  if (threadIdx.x < NG) lcnt[threadIdx.x] = 0.0f;
  __syncthreads();
  int lane = threadIdx.x & 63;
  int wid = threadIdx.x >> 6;
  int wavesTotal = (gridDim.x * blockDim.x) >> 6;
  for (int n = blockIdx.x * 4 + wid; n < N; n += wavesTotal) {
    int g = gid[n];
    float v = h[(size_t)n * DIM + lane];
    atomicAdd(&lsum[g * DIM + lane], v);
    if (lane == 0) atomicAdd(&lcnt[g], 1.0f);
  }
  __syncthreads();
  for (int t = threadIdx.x; t < NG * DIM; t += blockDim.x) atomicAdd(&gsum[t], lsum[t]);
  if (threadIdx.x < NG) atomicAdd(&gcnt[threadIdx.x], lcnt[threadIdx.x]);
}

// ---- head: out[g][c] = mean(h_g) @ Wp + bp ; single wave ----
__global__ void final_kernel(const float* __restrict__ gsum, const float* __restrict__ gcnt,
                             const float* __restrict__ Wp, const float* __restrict__ bp,
                             float* __restrict__ out) {
  int lane = threadIdx.x;  // 64 threads
#pragma unroll
  for (int g = 0; g < NG; ++g) {
    float inv = 1.0f / fmaxf(gcnt[g], 1.0f);
    float hv = gsum[g * DIM + lane] * inv;
#pragma unroll
    for (int c = 0; c < 2; ++c) {
      float p = hv * Wp[lane * 2 + c];
      for (int off = 32; off; off >>= 1) p += __shfl_down(p, off, 64);
      if (lane == 0) out[g * 2 + c] = p + bp[c];
    }
  }
}

extern "C" void kernel_launch(void* const* d_in, const int* in_sizes, int n_in,
                              void* d_out, int out_size, void* d_ws, size_t ws_size,
                              hipStream_t stream) {
  const float* features = (const float*)d_in[0];
  const float* W1 = (const float*)d_in[1];
  const float* b1 = (const float*)d_in[2];
  const float* W2 = (const float*)d_in[3];
  const float* b2 = (const float*)d_in[4];
  const float* Wp = (const float*)d_in[5];
  const float* bp = (const float*)d_in[6];
  const int* esrc = (const int*)d_in[7];
  const int* edst = (const int*)d_in[8];
  const int* gid = (const int*)d_in[9];
  float* out = (float*)d_out;

  const int N = NN, E = NE;
  float* f = (float*)d_ws;
  float* snorm = f;                       // [N]  out-deg -> rsqrt
  float* dnorm = f + N;                   // [N]  in-deg  -> rsqrt
  float* A = f + 2 * (size_t)N;           // [N*64]
  float* B = A + (size_t)N * DIM;         // [N*64]
  float* gsum = B + (size_t)N * DIM;      // [8*64]
  float* gcnt = gsum + NG * DIM;          // [8]
  size_t totalBytes = ((size_t)2 * N + 2 * (size_t)N * DIM + NG * DIM + NG) * sizeof(float);

  hipMemsetAsync(d_ws, 0, totalBytes, stream);

  degree_kernel<<<2048, 256, 0, stream>>>(esrc, edst, snorm, dnorm, E);
  norm_kernel<<<(N + 255) / 256, 256, 0, stream>>>(snorm, dnorm, N);

  // layer 1: features -> A (agg) -> A (h1, in place)
  scatter_kernel<<<8192, 256, 0, stream>>>(features, snorm, esrc, edst, A, E);
  node_mlp_kernel<<<2048, 256, 0, stream>>>(A, dnorm, W1, b1, N);

  // layer 2: A -> B (agg) -> B (h2, in place)
  scatter_kernel<<<8192, 256, 0, stream>>>(A, snorm, esrc, edst, B, E);
  node_mlp_kernel<<<2048, 256, 0, stream>>>(B, dnorm, W2, b2, N);

  pool_kernel<<<1024, 256, 0, stream>>>(B, gid, gsum, gcnt, N);
  final_kernel<<<1, 64, 0, stream>>>(gsum, gcnt, Wp, bp, out);
}

// Round 2
// 602.827 us; speedup vs baseline: 1.2740x; 1.2740x over previous
//
#include <hip/hip_runtime.h>

#define NN 100000
#define NE 1200000
#define NG 8
#define DIM 64
#define SCAN_BS 256
#define NB ((NN + SCAN_BS - 1) / SCAN_BS)  // 391

// ---- int degree histograms ----
__global__ void degree_kernel(const int* __restrict__ esrc, const int* __restrict__ edst,
                              int* __restrict__ outdeg, int* __restrict__ indeg, int E) {
  int i = blockIdx.x * blockDim.x + threadIdx.x;
  int st = gridDim.x * blockDim.x;
  for (; i < E; i += st) {
    atomicAdd(&outdeg[esrc[i]], 1);
    atomicAdd(&indeg[edst[i]], 1);
  }
}

// ---- deg -> rsqrt(max(deg,1)) ----
__global__ void norm_kernel(const int* __restrict__ outdeg, const int* __restrict__ indeg,
                            float* __restrict__ snorm, float* __restrict__ dnorm, int N) {
  int i = blockIdx.x * blockDim.x + threadIdx.x;
  if (i < N) {
    snorm[i] = rsqrtf(fmaxf((float)outdeg[i], 1.0f));
    dnorm[i] = rsqrtf(fmaxf((float)indeg[i], 1.0f));
  }
}

// ---- exclusive scan of indeg -> row_ptr (3 kernels) ----
__global__ __launch_bounds__(SCAN_BS) void scan1_kernel(const int* __restrict__ indeg,
                                                        int* __restrict__ rp,
                                                        int* __restrict__ bsum, int N) {
  __shared__ int t[SCAN_BS];
  int i = blockIdx.x * SCAN_BS + threadIdx.x;
  int v = (i < N) ? indeg[i] : 0;
  t[threadIdx.x] = v;
  __syncthreads();
  for (int off = 1; off < SCAN_BS; off <<= 1) {
    int u = (threadIdx.x >= off) ? t[threadIdx.x - off] : 0;
    __syncthreads();
    t[threadIdx.x] += u;
    __syncthreads();
  }
  if (i < N) rp[i] = t[threadIdx.x] - v;  // exclusive within block
  if (threadIdx.x == SCAN_BS - 1) bsum[blockIdx.x] = t[threadIdx.x];
}

__global__ __launch_bounds__(512) void scan2_kernel(const int* __restrict__ bsum,
                                                    int* __restrict__ boff, int nb) {
  __shared__ int t[512];
  int v = ((int)threadIdx.x < nb) ? bsum[threadIdx.x] : 0;
  t[threadIdx.x] = v;
  __syncthreads();
  for (int off = 1; off < 512; off <<= 1) {
    int u = (threadIdx.x >= off) ? t[threadIdx.x - off] : 0;
    __syncthreads();
    t[threadIdx.x] += u;
    __syncthreads();
  }
  boff[threadIdx.x] = t[threadIdx.x] - v;  // exclusive
}

__global__ __launch_bounds__(SCAN_BS) void scan3_kernel(int* __restrict__ rp,
                                                        const int* __restrict__ boff, int N) {
  int i = blockIdx.x * SCAN_BS + threadIdx.x;
  if (i < N) rp[i] += boff[blockIdx.x];
}

// ---- fill CSR col array (int atomics on per-node counters) ----
__global__ void fill_kernel(const int* __restrict__ esrc, const int* __restrict__ edst,
                            const int* __restrict__ rp, int* __restrict__ cnt,
                            int* __restrict__ col, int E) {
  int i = blockIdx.x * blockDim.x + threadIdx.x;
  int st = gridDim.x * blockDim.x;
  for (; i < E; i += st) {
    int d = edst[i];
    int p = atomicAdd(&cnt[d], 1);
    col[rp[d] + p] = esrc[i];
  }
}

// ---- fused gather + dnorm + matmul + relu (+ optional next-layer snorm prescale, optional pooling) ----
template <int PRESCALED, int POOL>
__global__ __launch_bounds__(256) void gconv_kernel(
    const float* __restrict__ x, const float* __restrict__ snorm, const float* __restrict__ dnorm,
    const int* __restrict__ rp, const int* __restrict__ deg, const int* __restrict__ col,
    const float* __restrict__ W, const float* __restrict__ b,
    float* __restrict__ out, const int* __restrict__ gid,
    float* __restrict__ gsum, float* __restrict__ gcnt, int N) {
  int lane = threadIdx.x & 63;
  int wid = threadIdx.x >> 6;

  // W column for this lane -> 64 VGPRs; bias -> 1 VGPR
  float wcol[DIM];
#pragma unroll
  for (int k = 0; k < DIM; ++k) wcol[k] = W[k * DIM + lane];
  float bv = b[lane];

  __shared__ float lsum[NG * DIM];
  __shared__ float lcnt[NG];
  if (POOL) {
    for (int t = threadIdx.x; t < NG * DIM; t += blockDim.x) lsum[t] = 0.0f;
    if (threadIdx.x < NG) lcnt[threadIdx.x] = 0.0f;
    __syncthreads();
  }

  int wavesTotal = (gridDim.x * blockDim.x) >> 6;
  for (int n = blockIdx.x * 4 + wid; n < N; n += wavesTotal) {
    int base = rp[n];
    int dg = deg[n];
    float acc = 0.0f;
    for (int j = 0; j < dg; ++j) {
      int s = col[base + j];              // lane-uniform -> broadcast load
      float v = x[(size_t)s * DIM + lane];  // coalesced 256B row
      if (!PRESCALED) v *= snorm[s];
      acc += v;
    }
    float a = acc * dnorm[n];
    float r = bv;
#pragma unroll
    for (int k = 0; k < DIM; ++k) {
      float ak = __uint_as_float(__builtin_amdgcn_readlane(__float_as_uint(a), k));
      r = fmaf(ak, wcol[k], r);
    }
    r = fmaxf(r, 0.0f);
    if (POOL) {
      int g = gid[n];
      atomicAdd(&lsum[g * DIM + lane], r);
      if (lane == 0) atomicAdd(&lcnt[g], 1.0f);
    } else {
      out[(size_t)n * DIM + lane] = r * snorm[n];  // prescale for next layer's gather
    }
  }

  if (POOL) {
    __syncthreads();
    for (int t = threadIdx.x; t < NG * DIM; t += blockDim.x) atomicAdd(&gsum[t], lsum[t]);
    if (threadIdx.x < NG) atomicAdd(&gcnt[threadIdx.x], lcnt[threadIdx.x]);
  }
}

// ---- head: out[g][c] = mean(h_g) @ Wp + bp ; single wave ----
__global__ void final_kernel(const float* __restrict__ gsum, const float* __restrict__ gcnt,
                             const float* __restrict__ Wp, const float* __restrict__ bp,
                             float* __restrict__ out) {
  int lane = threadIdx.x;  // 64 threads
#pragma unroll
  for (int g = 0; g < NG; ++g) {
    float inv = 1.0f / fmaxf(gcnt[g], 1.0f);
    float hv = gsum[g * DIM + lane] * inv;
#pragma unroll
    for (int c = 0; c < 2; ++c) {
      float p = hv * Wp[lane * 2 + c];
      for (int off = 32; off; off >>= 1) p += __shfl_down(p, off, 64);
      if (lane == 0) out[g * 2 + c] = p + bp[c];
    }
  }
}

extern "C" void kernel_launch(void* const* d_in, const int* in_sizes, int n_in,
                              void* d_out, int out_size, void* d_ws, size_t ws_size,
                              hipStream_t stream) {
  const float* features = (const float*)d_in[0];
  const float* W1 = (const float*)d_in[1];
  const float* b1 = (const float*)d_in[2];
  const float* W2 = (const float*)d_in[3];
  const float* b2 = (const float*)d_in[4];
  const float* Wp = (const float*)d_in[5];
  const float* bp = (const float*)d_in[6];
  const int* esrc = (const int*)d_in[7];
  const int* edst = (const int*)d_in[8];
  const int* gid = (const int*)d_in[9];
  float* out = (float*)d_out;

  const int N = NN, E = NE;

  // workspace layout (all 4-byte types)
  int* outdeg = (int*)d_ws;            // N  (zeroed)
  int* indeg = outdeg + N;             // N  (zeroed)
  int* cnt = indeg + N;                // N  (zeroed)
  float* gsum = (float*)(cnt + N);     // NG*DIM (zeroed)
  float* gcnt = gsum + NG * DIM;       // NG (zeroed)
  int* rp = (int*)(gcnt + NG);         // N
  int* bsum = rp + N;                  // 512
  int* boff = bsum + 512;              // 512
  int* col = boff + 512;               // E
  float* snorm = (float*)(col + E);    // N
  float* dnorm = snorm + N;            // N
  float* A = dnorm + N;                // N*DIM

  size_t zeroBytes = ((size_t)3 * N + NG * DIM + NG) * sizeof(int);
  hipMemsetAsync(d_ws, 0, zeroBytes, stream);

  degree_kernel<<<2048, 256, 0, stream>>>(esrc, edst, outdeg, indeg, E);
  norm_kernel<<<(N + 255) / 256, 256, 0, stream>>>(outdeg, indeg, snorm, dnorm, N);

  scan1_kernel<<<NB, SCAN_BS, 0, stream>>>(indeg, rp, bsum, N);
  scan2_kernel<<<1, 512, 0, stream>>>(bsum, boff, NB);
  scan3_kernel<<<NB, SCAN_BS, 0, stream>>>(rp, boff, N);

  fill_kernel<<<2048, 256, 0, stream>>>(esrc, edst, rp, cnt, col, E);

  // layer 1: features (unscaled) -> A = relu(...)*snorm  [prescaled for layer 2]
  gconv_kernel<0, 0><<<2048, 256, 0, stream>>>(features, snorm, dnorm, rp, indeg, col,
                                               W1, b1, A, gid, gsum, gcnt, N);
  // layer 2: A (prescaled) -> pooled gsum/gcnt directly (h2 never stored)
  gconv_kernel<1, 1><<<2048, 256, 0, stream>>>(A, snorm, dnorm, rp, indeg, col,
                                               W2, b2, nullptr, gid, gsum, gcnt, N);

  final_kernel<<<1, 64, 0, stream>>>(gsum, gcnt, Wp, bp, out);
}

// Round 3
// 409.196 us; speedup vs baseline: 1.8769x; 1.4732x over previous
//
#include <hip/hip_runtime.h>

#define NN 100000
#define NE 1200000
#define NG 8
#define DIM 64
#define SCAN_BS 256
#define NB ((NN + SCAN_BS - 1) / SCAN_BS)  // 391

__device__ __forceinline__ float readlane_f(float v, int l) {
  return __uint_as_float(__builtin_amdgcn_readlane(__float_as_uint(v), l));
}

// ---- int degree histograms ----
__global__ void degree_kernel(const int* __restrict__ esrc, const int* __restrict__ edst,
                              int* __restrict__ outdeg, int* __restrict__ indeg, int E) {
  int i = blockIdx.x * blockDim.x + threadIdx.x;
  int st = gridDim.x * blockDim.x;
  for (; i < E; i += st) {
    atomicAdd(&outdeg[esrc[i]], 1);
    atomicAdd(&indeg[edst[i]], 1);
  }
}

// ---- deg -> rsqrt(max(deg,1)) ----
__global__ void norm_kernel(const int* __restrict__ outdeg, const int* __restrict__ indeg,
                            float* __restrict__ snorm, float* __restrict__ dnorm, int N) {
  int i = blockIdx.x * blockDim.x + threadIdx.x;
  if (i < N) {
    snorm[i] = rsqrtf(fmaxf((float)outdeg[i], 1.0f));
    dnorm[i] = rsqrtf(fmaxf((float)indeg[i], 1.0f));
  }
}

// ---- exclusive scan of indeg -> row_ptr (3 kernels) ----
__global__ __launch_bounds__(SCAN_BS) void scan1_kernel(const int* __restrict__ indeg,
                                                        int* __restrict__ rp,
                                                        int* __restrict__ bsum, int N) {
  __shared__ int t[SCAN_BS];
  int i = blockIdx.x * SCAN_BS + threadIdx.x;
  int v = (i < N) ? indeg[i] : 0;
  t[threadIdx.x] = v;
  __syncthreads();
  for (int off = 1; off < SCAN_BS; off <<= 1) {
    int u = (threadIdx.x >= off) ? t[threadIdx.x - off] : 0;
    __syncthreads();
    t[threadIdx.x] += u;
    __syncthreads();
  }
  if (i < N) rp[i] = t[threadIdx.x] - v;
  if (threadIdx.x == SCAN_BS - 1) bsum[blockIdx.x] = t[threadIdx.x];
}

__global__ __launch_bounds__(512) void scan2_kernel(const int* __restrict__ bsum,
                                                    int* __restrict__ boff, int nb) {
  __shared__ int t[512];
  int v = ((int)threadIdx.x < nb) ? bsum[threadIdx.x] : 0;
  t[threadIdx.x] = v;
  __syncthreads();
  for (int off = 1; off < 512; off <<= 1) {
    int u = (threadIdx.x >= off) ? t[threadIdx.x - off] : 0;
    __syncthreads();
    t[threadIdx.x] += u;
    __syncthreads();
  }
  boff[threadIdx.x] = t[threadIdx.x] - v;
}

__global__ __launch_bounds__(SCAN_BS) void scan3_kernel(int* __restrict__ rp,
                                                        const int* __restrict__ boff, int N) {
  int i = blockIdx.x * SCAN_BS + threadIdx.x;
  if (i < N) rp[i] += boff[blockIdx.x];
}

// ---- fill CSR col array ----
__global__ void fill_kernel(const int* __restrict__ esrc, const int* __restrict__ edst,
                            const int* __restrict__ rp, int* __restrict__ cnt,
                            int* __restrict__ col, int E) {
  int i = blockIdx.x * blockDim.x + threadIdx.x;
  int st = gridDim.x * blockDim.x;
  for (; i < E; i += st) {
    int d = edst[i];
    int p = atomicAdd(&cnt[d], 1);
    col[rp[d] + p] = esrc[i];
  }
}

// ---- fused gather + dnorm + matmul + relu (+ prescale next layer / pool) ----
template <int PRESCALED, int POOL>
__global__ __launch_bounds__(256) void gconv_kernel(
    const float* __restrict__ x, const float* __restrict__ snorm, const float* __restrict__ dnorm,
    const int* __restrict__ rp, const int* __restrict__ deg, const int* __restrict__ col,
    const float* __restrict__ W, const float* __restrict__ b,
    float* __restrict__ out, const int* __restrict__ gid,
    float* __restrict__ gsum, float* __restrict__ gcnt, int N) {
  __shared__ float Wl[DIM * DIM];
  __shared__ float lsum[NG * DIM];
  __shared__ float lcnt[NG];
  for (int t = threadIdx.x; t < DIM * DIM; t += blockDim.x) Wl[t] = W[t];
  if (POOL) {
    for (int t = threadIdx.x; t < NG * DIM; t += blockDim.x) lsum[t] = 0.0f;
    if (threadIdx.x < NG) lcnt[threadIdx.x] = 0.0f;
  }
  __syncthreads();

  int lane = threadIdx.x & 63;
  int wid = threadIdx.x >> 6;
  float bv = b[lane];
  int wavesTotal = gridDim.x * 4;

  for (int n = blockIdx.x * 4 + wid; n < N; n += wavesTotal) {
    int base = rp[n];
    int dg = deg[n];
    float acc[8];
#pragma unroll
    for (int u = 0; u < 8; ++u) acc[u] = 0.0f;

    for (int c = 0; c < dg; c += 64) {
      int m = min(64, dg - c);
      // cooperative: lane j holds col/snorm for edge c+j
      int myCol = (lane < m) ? col[base + c + lane] : 0;
      float myS = 1.0f;
      if (!PRESCALED) myS = (lane < m) ? snorm[myCol] : 1.0f;
      int j = 0;
      for (; j + 8 <= m; j += 8) {
#pragma unroll
        for (int u = 0; u < 8; ++u) {
          int s = __builtin_amdgcn_readlane(myCol, j + u);
          float v = x[(size_t)s * DIM + lane];
          if (PRESCALED) acc[u] += v;
          else acc[u] = fmaf(v, readlane_f(myS, j + u), acc[u]);
        }
      }
      for (; j < m; ++j) {
        int s = __builtin_amdgcn_readlane(myCol, j);
        float v = x[(size_t)s * DIM + lane];
        if (PRESCALED) acc[0] += v;
        else acc[0] = fmaf(v, readlane_f(myS, j), acc[0]);
      }
    }
    float a = ((acc[0] + acc[1]) + (acc[2] + acc[3])) +
              ((acc[4] + acc[5]) + (acc[6] + acc[7]));
    a *= dnorm[n];

    // MLP: r = relu(a_row @ W + b), 4-way split accumulators
    float r0 = bv, r1 = 0.0f, r2 = 0.0f, r3 = 0.0f;
#pragma unroll
    for (int k = 0; k < DIM; k += 4) {
      r0 = fmaf(readlane_f(a, k + 0), Wl[(k + 0) * DIM + lane], r0);
      r1 = fmaf(readlane_f(a, k + 1), Wl[(k + 1) * DIM + lane], r1);
      r2 = fmaf(readlane_f(a, k + 2), Wl[(k + 2) * DIM + lane], r2);
      r3 = fmaf(readlane_f(a, k + 3), Wl[(k + 3) * DIM + lane], r3);
    }
    float r = fmaxf((r0 + r1) + (r2 + r3), 0.0f);

    if (POOL) {
      int g = gid[n];
      atomicAdd(&lsum[g * DIM + lane], r);
      if (lane == 0) atomicAdd(&lcnt[g], 1.0f);
    } else {
      out[(size_t)n * DIM + lane] = r * snorm[n];  // prescale for next layer
    }
  }

  if (POOL) {
    __syncthreads();
    for (int t = threadIdx.x; t < NG * DIM; t += blockDim.x) atomicAdd(&gsum[t], lsum[t]);
    if (threadIdx.x < NG) atomicAdd(&gcnt[threadIdx.x], lcnt[threadIdx.x]);
  }
}

// ---- head ----
__global__ void final_kernel(const float* __restrict__ gsum, const float* __restrict__ gcnt,
                             const float* __restrict__ Wp, const float* __restrict__ bp,
                             float* __restrict__ out) {
  int lane = threadIdx.x;  // 64
#pragma unroll
  for (int g = 0; g < NG; ++g) {
    float inv = 1.0f / fmaxf(gcnt[g], 1.0f);
    float hv = gsum[g * DIM + lane] * inv;
#pragma unroll
    for (int c = 0; c < 2; ++c) {
      float p = hv * Wp[lane * 2 + c];
      for (int off = 32; off; off >>= 1) p += __shfl_down(p, off, 64);
      if (lane == 0) out[g * 2 + c] = p + bp[c];
    }
  }
}

extern "C" void kernel_launch(void* const* d_in, const int* in_sizes, int n_in,
                              void* d_out, int out_size, void* d_ws, size_t ws_size,
                              hipStream_t stream) {
  const float* features = (const float*)d_in[0];
  const float* W1 = (const float*)d_in[1];
  const float* b1 = (const float*)d_in[2];
  const float* W2 = (const float*)d_in[3];
  const float* b2 = (const float*)d_in[4];
  const float* Wp = (const float*)d_in[5];
  const float* bp = (const float*)d_in[6];
  const int* esrc = (const int*)d_in[7];
  const int* edst = (const int*)d_in[8];
  const int* gid = (const int*)d_in[9];
  float* out = (float*)d_out;

  const int N = NN, E = NE;

  // workspace: zeroed region first
  int* outdeg = (int*)d_ws;            // N
  int* indeg = outdeg + N;             // N
  int* cnt = indeg + N;                // N
  float* gsum = (float*)(cnt + N);     // NG*DIM
  float* gcnt = gsum + NG * DIM;       // NG
  int* rp = (int*)(gcnt + NG);         // N
  int* bsum = rp + N;                  // 512
  int* boff = bsum + 512;              // 512
  int* col = boff + 512;               // E
  float* snorm = (float*)(col + E);    // N
  float* dnorm = snorm + N;            // N
  float* A = dnorm + N;                // N*DIM

  size_t zeroBytes = ((size_t)3 * N + NG * DIM + NG) * sizeof(int);
  hipMemsetAsync(d_ws, 0, zeroBytes, stream);

  degree_kernel<<<2048, 256, 0, stream>>>(esrc, edst, outdeg, indeg, E);
  norm_kernel<<<(N + 255) / 256, 256, 0, stream>>>(outdeg, indeg, snorm, dnorm, N);

  scan1_kernel<<<NB, SCAN_BS, 0, stream>>>(indeg, rp, bsum, N);
  scan2_kernel<<<1, 512, 0, stream>>>(bsum, boff, NB);
  scan3_kernel<<<NB, SCAN_BS, 0, stream>>>(rp, boff, N);

  fill_kernel<<<2048, 256, 0, stream>>>(esrc, edst, rp, cnt, col, E);

  gconv_kernel<0, 0><<<2048, 256, 0, stream>>>(features, snorm, dnorm, rp, indeg, col,
                                               W1, b1, A, gid, gsum, gcnt, N);
  gconv_kernel<1, 1><<<2048, 256, 0, stream>>>(A, snorm, dnorm, rp, indeg, col,
                                               W2, b2, nullptr, gid, gsum, gcnt, N);

  final_kernel<<<1, 64, 0, stream>>>(gsum, gcnt, Wp, bp, out);
}

// Round 4
// 374.607 us; speedup vs baseline: 2.0502x; 1.0923x over previous
//
#include <hip/hip_runtime.h>

#define NN 100000
#define NE 1200000
#define NG 8
#define DIM 64
#define SCAN_BS 256
#define NB ((NN + SCAN_BS - 1) / SCAN_BS)  // 391

__device__ __forceinline__ float readlane_f(float v, int l) {
  return __uint_as_float(__builtin_amdgcn_readlane(__float_as_uint(v), l));
}

// ---- int degree histograms ----
__global__ void degree_kernel(const int* __restrict__ esrc, const int* __restrict__ edst,
                              int* __restrict__ outdeg, int* __restrict__ indeg, int E) {
  int i = blockIdx.x * blockDim.x + threadIdx.x;
  int st = gridDim.x * blockDim.x;
  for (; i < E; i += st) {
    atomicAdd(&outdeg[esrc[i]], 1);
    atomicAdd(&indeg[edst[i]], 1);
  }
}

// ---- deg -> rsqrt(max(deg,1)) ----
__global__ void norm_kernel(const int* __restrict__ outdeg, const int* __restrict__ indeg,
                            float* __restrict__ snorm, float* __restrict__ dnorm, int N) {
  int i = blockIdx.x * blockDim.x + threadIdx.x;
  if (i < N) {
    snorm[i] = rsqrtf(fmaxf((float)outdeg[i], 1.0f));
    dnorm[i] = rsqrtf(fmaxf((float)indeg[i], 1.0f));
  }
}

// ---- exclusive scan of indeg -> row_ptr ----
__global__ __launch_bounds__(SCAN_BS) void scan1_kernel(const int* __restrict__ indeg,
                                                        int* __restrict__ rp,
                                                        int* __restrict__ bsum, int N) {
  __shared__ int t[SCAN_BS];
  int i = blockIdx.x * SCAN_BS + threadIdx.x;
  int v = (i < N) ? indeg[i] : 0;
  t[threadIdx.x] = v;
  __syncthreads();
  for (int off = 1; off < SCAN_BS; off <<= 1) {
    int u = (threadIdx.x >= off) ? t[threadIdx.x - off] : 0;
    __syncthreads();
    t[threadIdx.x] += u;
    __syncthreads();
  }
  if (i < N) rp[i] = t[threadIdx.x] - v;
  if (threadIdx.x == SCAN_BS - 1) bsum[blockIdx.x] = t[threadIdx.x];
}

__global__ __launch_bounds__(512) void scan2_kernel(const int* __restrict__ bsum,
                                                    int* __restrict__ boff, int nb) {
  __shared__ int t[512];
  int v = ((int)threadIdx.x < nb) ? bsum[threadIdx.x] : 0;
  t[threadIdx.x] = v;
  __syncthreads();
  for (int off = 1; off < 512; off <<= 1) {
    int u = (threadIdx.x >= off) ? t[threadIdx.x - off] : 0;
    __syncthreads();
    t[threadIdx.x] += u;
    __syncthreads();
  }
  boff[threadIdx.x] = t[threadIdx.x] - v;
}

__global__ __launch_bounds__(SCAN_BS) void scan3_kernel(int* __restrict__ rp,
                                                        const int* __restrict__ boff, int N) {
  int i = blockIdx.x * SCAN_BS + threadIdx.x;
  if (i < N) rp[i] += boff[blockIdx.x];
}

// ---- fill CSR col array ----
__global__ void fill_kernel(const int* __restrict__ esrc, const int* __restrict__ edst,
                            const int* __restrict__ rp, int* __restrict__ cnt,
                            int* __restrict__ col, int E) {
  int i = blockIdx.x * blockDim.x + threadIdx.x;
  int st = gridDim.x * blockDim.x;
  for (; i < E; i += st) {
    int d = edst[i];
    int p = atomicAdd(&cnt[d], 1);
    col[rp[d] + p] = esrc[i];
  }
}

// ---- fused gather(float4, quad-parallel) + dnorm + matmul + relu ----
// PRESCALED=0: weight each source row by snorm[src] (pads get w=0).
// PRESCALED=1: rows pre-scaled; pads redirect to zero row at index NN.
template <int PRESCALED, int POOL>
__global__ __launch_bounds__(256) void gconv_kernel(
    const float* __restrict__ x, const float* __restrict__ snorm, const float* __restrict__ dnorm,
    const int* __restrict__ rp, const int* __restrict__ deg, const int* __restrict__ col,
    const float* __restrict__ W, const float* __restrict__ b,
    float* __restrict__ out, const int* __restrict__ gid,
    float* __restrict__ gsum, float* __restrict__ gcnt, int N) {
  __shared__ float Wt[DIM * DIM];  // transposed + XOR-swizzled: W[k][l] at word l*64 + 4*(k/4 ^ (l&7)) + k%4
  __shared__ float lsum[NG * DIM];
  __shared__ float lcnt[NG];
  for (int idx = threadIdx.x; idx < DIM * 16; idx += blockDim.x) {
    int l = idx >> 4, kc = idx & 15;
    int dst = (l << 6) + (((kc ^ (l & 7)) << 2));
#pragma unroll
    for (int cc = 0; cc < 4; ++cc) Wt[dst + cc] = W[(kc * 4 + cc) * DIM + l];
  }
  if (POOL) {
    for (int t = threadIdx.x; t < NG * DIM; t += blockDim.x) lsum[t] = 0.0f;
    if (threadIdx.x < NG) lcnt[threadIdx.x] = 0.0f;
  }
  __syncthreads();

  int lane = threadIdx.x & 63;
  int wid = threadIdx.x >> 6;
  int q = lane >> 4;        // quad id: which edge within a group of 4
  int t4 = (lane & 15) * 4; // this lane's dim-chunk offset
  float bv = b[lane];
  int wavesTotal = gridDim.x * 4;
  const int swz = ((lane & 7) << 2);
  const int lbase = (lane << 6);

  for (int n = blockIdx.x * 4 + wid; n < N; n += wavesTotal) {
    int base = rp[n];
    int dg = deg[n];
    float4 acc0 = make_float4(0.f, 0.f, 0.f, 0.f);
    float4 acc1 = make_float4(0.f, 0.f, 0.f, 0.f);

    for (int c0 = 0; c0 < dg; c0 += 64) {
      int m = min(64, dg - c0);
      int myCol;
      float myW = 0.0f;
      if (PRESCALED) {
        myCol = (lane < m) ? col[base + c0 + lane] : NN;  // pad -> zero row
      } else {
        myCol = (lane < m) ? col[base + c0 + lane] : 0;
        if (lane < m) myW = snorm[myCol];
      }
      int ng = (m + 3) >> 2;
      int g = 0;
      for (; g + 2 <= ng; g += 2) {
        int j0 = g * 4 + q, j1 = j0 + 4;
        int s0 = __shfl(myCol, j0, 64);
        int s1 = __shfl(myCol, j1, 64);
        float4 v0 = *(const float4*)(x + (size_t)s0 * DIM + t4);
        float4 v1 = *(const float4*)(x + (size_t)s1 * DIM + t4);
        if (PRESCALED) {
          acc0.x += v0.x; acc0.y += v0.y; acc0.z += v0.z; acc0.w += v0.w;
          acc1.x += v1.x; acc1.y += v1.y; acc1.z += v1.z; acc1.w += v1.w;
        } else {
          float w0 = __shfl(myW, j0, 64);
          float w1 = __shfl(myW, j1, 64);
          acc0.x = fmaf(v0.x, w0, acc0.x); acc0.y = fmaf(v0.y, w0, acc0.y);
          acc0.z = fmaf(v0.z, w0, acc0.z); acc0.w = fmaf(v0.w, w0, acc0.w);
          acc1.x = fmaf(v1.x, w1, acc1.x); acc1.y = fmaf(v1.y, w1, acc1.y);
          acc1.z = fmaf(v1.z, w1, acc1.z); acc1.w = fmaf(v1.w, w1, acc1.w);
        }
      }
      if (g < ng) {
        int j0 = g * 4 + q;
        int s0 = __shfl(myCol, j0, 64);
        float4 v0 = *(const float4*)(x + (size_t)s0 * DIM + t4);
        if (PRESCALED) {
          acc0.x += v0.x; acc0.y += v0.y; acc0.z += v0.z; acc0.w += v0.w;
        } else {
          float w0 = __shfl(myW, j0, 64);
          acc0.x = fmaf(v0.x, w0, acc0.x); acc0.y = fmaf(v0.y, w0, acc0.y);
          acc0.z = fmaf(v0.z, w0, acc0.z); acc0.w = fmaf(v0.w, w0, acc0.w);
        }
      }
    }

    // combine unroll pair, reduce across quads (lanes ^16, ^32)
    float4 acc;
    acc.x = acc0.x + acc1.x; acc.y = acc0.y + acc1.y;
    acc.z = acc0.z + acc1.z; acc.w = acc0.w + acc1.w;
    acc.x += __shfl_xor(acc.x, 16, 64); acc.x += __shfl_xor(acc.x, 32, 64);
    acc.y += __shfl_xor(acc.y, 16, 64); acc.y += __shfl_xor(acc.y, 32, 64);
    acc.z += __shfl_xor(acc.z, 16, 64); acc.z += __shfl_xor(acc.z, 32, 64);
    acc.w += __shfl_xor(acc.w, 16, 64); acc.w += __shfl_xor(acc.w, 32, 64);
    float dn = dnorm[n];
    acc.x *= dn; acc.y *= dn; acc.z *= dn; acc.w *= dn;

    // MLP: r[lane] = relu(b[lane] + sum_k a[k]*W[k][lane]); a[4kc+c] lives in lane kc comp c
    float r0 = bv, r1 = 0.f, r2 = 0.f, r3 = 0.f;
#pragma unroll
    for (int kc = 0; kc < 16; ++kc) {
      float4 wv = *(const float4*)(Wt + lbase + (((kc << 2) ^ swz)));
      r0 = fmaf(readlane_f(acc.x, kc), wv.x, r0);
      r1 = fmaf(readlane_f(acc.y, kc), wv.y, r1);
      r2 = fmaf(readlane_f(acc.z, kc), wv.z, r2);
      r3 = fmaf(readlane_f(acc.w, kc), wv.w, r3);
    }
    float r = fmaxf((r0 + r1) + (r2 + r3), 0.0f);

    if (POOL) {
      int g = gid[n];
      atomicAdd(&lsum[g * DIM + lane], r);
      if (lane == 0) atomicAdd(&lcnt[g], 1.0f);
    } else {
      out[(size_t)n * DIM + lane] = r * snorm[n];  // prescale for next layer
    }
  }

  if (POOL) {
    __syncthreads();
    for (int t = threadIdx.x; t < NG * DIM; t += blockDim.x) atomicAdd(&gsum[t], lsum[t]);
    if (threadIdx.x < NG) atomicAdd(&gcnt[threadIdx.x], lcnt[threadIdx.x]);
  }
}

// ---- head ----
__global__ void final_kernel(const float* __restrict__ gsum, const float* __restrict__ gcnt,
                             const float* __restrict__ Wp, const float* __restrict__ bp,
                             float* __restrict__ out) {
  int lane = threadIdx.x;  // 64
#pragma unroll
  for (int g = 0; g < NG; ++g) {
    float inv = 1.0f / fmaxf(gcnt[g], 1.0f);
    float hv = gsum[g * DIM + lane] * inv;
#pragma unroll
    for (int c = 0; c < 2; ++c) {
      float p = hv * Wp[lane * 2 + c];
      for (int off = 32; off; off >>= 1) p += __shfl_down(p, off, 64);
      if (lane == 0) out[g * 2 + c] = p + bp[c];
    }
  }
}

extern "C" void kernel_launch(void* const* d_in, const int* in_sizes, int n_in,
                              void* d_out, int out_size, void* d_ws, size_t ws_size,
                              hipStream_t stream) {
  const float* features = (const float*)d_in[0];
  const float* W1 = (const float*)d_in[1];
  const float* b1 = (const float*)d_in[2];
  const float* W2 = (const float*)d_in[3];
  const float* b2 = (const float*)d_in[4];
  const float* Wp = (const float*)d_in[5];
  const float* bp = (const float*)d_in[6];
  const int* esrc = (const int*)d_in[7];
  const int* edst = (const int*)d_in[8];
  const int* gid = (const int*)d_in[9];
  float* out = (float*)d_out;

  const int N = NN, E = NE;

  // workspace: zeroed region first
  int* outdeg = (int*)d_ws;            // N
  int* indeg = outdeg + N;             // N
  int* cnt = indeg + N;                // N
  float* gsum = (float*)(cnt + N);     // NG*DIM
  float* gcnt = gsum + NG * DIM;       // NG
  int* rp = (int*)(gcnt + NG);         // N
  int* bsum = rp + N;                  // 512
  int* boff = bsum + 512;              // 512
  int* col = boff + 512;               // E
  float* snorm = (float*)(col + E);    // N
  float* dnorm = snorm + N;            // N
  float* A = dnorm + N;                // (N+1)*DIM, row N is the zero row

  size_t zeroBytes = ((size_t)3 * N + NG * DIM + NG) * sizeof(int);
  hipMemsetAsync(d_ws, 0, zeroBytes, stream);
  hipMemsetAsync(A + (size_t)N * DIM, 0, DIM * sizeof(float), stream);  // zero row

  degree_kernel<<<2048, 256, 0, stream>>>(esrc, edst, outdeg, indeg, E);
  norm_kernel<<<(N + 255) / 256, 256, 0, stream>>>(outdeg, indeg, snorm, dnorm, N);

  scan1_kernel<<<NB, SCAN_BS, 0, stream>>>(indeg, rp, bsum, N);
  scan2_kernel<<<1, 512, 0, stream>>>(bsum, boff, NB);
  scan3_kernel<<<NB, SCAN_BS, 0, stream>>>(rp, boff, N);

  fill_kernel<<<2048, 256, 0, stream>>>(esrc, edst, rp, cnt, col, E);

  gconv_kernel<0, 0><<<2048, 256, 0, stream>>>(features, snorm, dnorm, rp, indeg, col,
                                               W1, b1, A, gid, gsum, gcnt, N);
  gconv_kernel<1, 1><<<2048, 256, 0, stream>>>(A, snorm, dnorm, rp, indeg, col,
                                               W2, b2, nullptr, gid, gsum, gcnt, N);

  final_kernel<<<1, 64, 0, stream>>>(gsum, gcnt, Wp, bp, out);
}

// Round 5
// 344.964 us; speedup vs baseline: 2.2264x; 1.0859x over previous
//
#include <hip/hip_runtime.h>

#define NN 100000
#define NE 1200000
#define NG 8
#define DIM 64
#define WROW 68  // padded LDS row (words) to break bank-cycle alignment
#define SCAN_BS 256
#define NB ((NN + SCAN_BS - 1) / SCAN_BS)  // 391

// ---- int degree histograms ----
__global__ void degree_kernel(const int* __restrict__ esrc, const int* __restrict__ edst,
                              int* __restrict__ outdeg, int* __restrict__ indeg, int E) {
  int i = blockIdx.x * blockDim.x + threadIdx.x;
  int st = gridDim.x * blockDim.x;
  for (; i < E; i += st) {
    atomicAdd(&outdeg[esrc[i]], 1);
    atomicAdd(&indeg[edst[i]], 1);
  }
}

// ---- deg -> rsqrt(max(deg,1)) ----
__global__ void norm_kernel(const int* __restrict__ outdeg, const int* __restrict__ indeg,
                            float* __restrict__ snorm, float* __restrict__ dnorm, int N) {
  int i = blockIdx.x * blockDim.x + threadIdx.x;
  if (i < N) {
    snorm[i] = rsqrtf(fmaxf((float)outdeg[i], 1.0f));
    dnorm[i] = rsqrtf(fmaxf((float)indeg[i], 1.0f));
  }
}

// ---- exclusive scan of indeg -> row_ptr ----
__global__ __launch_bounds__(SCAN_BS) void scan1_kernel(const int* __restrict__ indeg,
                                                        int* __restrict__ rp,
                                                        int* __restrict__ bsum, int N) {
  __shared__ int t[SCAN_BS];
  int i = blockIdx.x * SCAN_BS + threadIdx.x;
  int v = (i < N) ? indeg[i] : 0;
  t[threadIdx.x] = v;
  __syncthreads();
  for (int off = 1; off < SCAN_BS; off <<= 1) {
    int u = (threadIdx.x >= off) ? t[threadIdx.x - off] : 0;
    __syncthreads();
    t[threadIdx.x] += u;
    __syncthreads();
  }
  if (i < N) rp[i] = t[threadIdx.x] - v;
  if (threadIdx.x == SCAN_BS - 1) bsum[blockIdx.x] = t[threadIdx.x];
}

__global__ __launch_bounds__(512) void scan2_kernel(const int* __restrict__ bsum,
                                                    int* __restrict__ boff, int nb) {
  __shared__ int t[512];
  int v = ((int)threadIdx.x < nb) ? bsum[threadIdx.x] : 0;
  t[threadIdx.x] = v;
  __syncthreads();
  for (int off = 1; off < 512; off <<= 1) {
    int u = (threadIdx.x >= off) ? t[threadIdx.x - off] : 0;
    __syncthreads();
    t[threadIdx.x] += u;
    __syncthreads();
  }
  boff[threadIdx.x] = t[threadIdx.x] - v;
}

__global__ __launch_bounds__(SCAN_BS) void scan3_kernel(int* __restrict__ rp,
                                                        const int* __restrict__ boff, int N) {
  int i = blockIdx.x * SCAN_BS + threadIdx.x;
  if (i < N) rp[i] += boff[blockIdx.x];
}

// ---- fill CSR col array ----
__global__ void fill_kernel(const int* __restrict__ esrc, const int* __restrict__ edst,
                            const int* __restrict__ rp, int* __restrict__ cnt,
                            int* __restrict__ col, int E) {
  int i = blockIdx.x * blockDim.x + threadIdx.x;
  int st = gridDim.x * blockDim.x;
  for (; i < E; i += st) {
    int d = edst[i];
    int p = atomicAdd(&cnt[d], 1);
    col[rp[d] + p] = esrc[i];
  }
}

// ---- fused gather + dnorm + matmul + relu; 4 nodes per wave (16 lanes each) ----
// PRESCALED=0: weight rows by snorm[src]; pad slots use col=0, w=0 (row 0 stays L1-hot).
// PRESCALED=1: rows pre-scaled; pad slots redirect to zero row at index NN.
template <int PRESCALED, int POOL>
__global__ __launch_bounds__(256) void gconv_kernel(
    const float* __restrict__ x, const float* __restrict__ snorm, const float* __restrict__ dnorm,
    const int* __restrict__ rp, const int* __restrict__ deg, const int* __restrict__ col,
    const float* __restrict__ W, const float* __restrict__ b,
    float* __restrict__ out, const int* __restrict__ gid,
    float* __restrict__ gsum, float* __restrict__ gcnt, int N) {
  __shared__ float Wt[DIM * WROW];  // W row-major, rows padded to 68 words
  __shared__ float lsum[NG * DIM];
  __shared__ float lcnt[NG];
  for (int i = threadIdx.x; i < DIM * 16; i += blockDim.x) {
    int k = i >> 4, ch = i & 15;
#pragma unroll
    for (int c = 0; c < 4; ++c) Wt[k * WROW + ch * 4 + c] = W[k * DIM + ch * 4 + c];
  }
  if (POOL) {
    for (int t = threadIdx.x; t < NG * DIM; t += blockDim.x) lsum[t] = 0.0f;
    if (threadIdx.x < NG) lcnt[threadIdx.x] = 0.0f;
  }
  __syncthreads();

  const int lane = threadIdx.x & 63;
  const int wid = threadIdx.x >> 6;
  const int g = lane >> 4;   // group = which node of the 4
  const int idx = lane & 15; // lane within group: edge slot / dim chunk
  const int t4 = idx * 4;
  const int gb = lane & 48;  // group base lane for shfl
  const float4 bb = *(const float4*)(b + t4);

  const int waveId = blockIdx.x * 4 + wid;
  const int stride4 = gridDim.x * 16;

  for (int n4 = waveId * 4; n4 < N; n4 += stride4) {
    int n = n4 + g;
    bool valid = n < N;
    int nc = valid ? n : 0;
    int base = rp[nc];
    int dg = valid ? deg[nc] : 0;
    float dn = dnorm[nc];

    float4 acc = make_float4(0.f, 0.f, 0.f, 0.f);
    for (int c0 = 0; c0 < dg; c0 += 16) {
      int m = min(16, dg - c0);
      int myCol;
      float myW;
      if (PRESCALED) {
        myCol = (idx < m) ? col[base + c0 + idx] : NN;  // pad -> zero row
      } else {
        myCol = (idx < m) ? col[base + c0 + idx] : 0;   // pad -> row 0, weight 0
        myW = (idx < m) ? snorm[myCol] : 0.0f;
      }
      int mr = (m + 3) & ~3;
      for (int j = 0; j < mr; j += 4) {
        int s0 = __shfl(myCol, gb + j + 0, 64);
        int s1 = __shfl(myCol, gb + j + 1, 64);
        int s2 = __shfl(myCol, gb + j + 2, 64);
        int s3 = __shfl(myCol, gb + j + 3, 64);
        float4 v0 = *(const float4*)(x + (size_t)s0 * DIM + t4);
        float4 v1 = *(const float4*)(x + (size_t)s1 * DIM + t4);
        float4 v2 = *(const float4*)(x + (size_t)s2 * DIM + t4);
        float4 v3 = *(const float4*)(x + (size_t)s3 * DIM + t4);
        if (PRESCALED) {
          acc.x += v0.x + v1.x + v2.x + v3.x;
          acc.y += v0.y + v1.y + v2.y + v3.y;
          acc.z += v0.z + v1.z + v2.z + v3.z;
          acc.w += v0.w + v1.w + v2.w + v3.w;
        } else {
          float w0 = __shfl(myW, gb + j + 0, 64);
          float w1 = __shfl(myW, gb + j + 1, 64);
          float w2 = __shfl(myW, gb + j + 2, 64);
          float w3 = __shfl(myW, gb + j + 3, 64);
          acc.x = fmaf(v0.x, w0, fmaf(v1.x, w1, fmaf(v2.x, w2, fmaf(v3.x, w3, acc.x))));
          acc.y = fmaf(v0.y, w0, fmaf(v1.y, w1, fmaf(v2.y, w2, fmaf(v3.y, w3, acc.y))));
          acc.z = fmaf(v0.z, w0, fmaf(v1.z, w1, fmaf(v2.z, w2, fmaf(v3.z, w3, acc.z))));
          acc.w = fmaf(v0.w, w0, fmaf(v1.w, w1, fmaf(v2.w, w2, fmaf(v3.w, w3, acc.w))));
        }
      }
    }
    acc.x *= dn; acc.y *= dn; acc.z *= dn; acc.w *= dn;

    // MLP: lane owns out dims t4..t4+3 of its group's node.
    // a[4kc+c] lives in lane (gb+kc) component c.
    float4 r = bb;
#pragma unroll
    for (int kc = 0; kc < 16; ++kc) {
      float a0 = __shfl(acc.x, gb + kc, 64);
      float a1 = __shfl(acc.y, gb + kc, 64);
      float a2 = __shfl(acc.z, gb + kc, 64);
      float a3 = __shfl(acc.w, gb + kc, 64);
      float4 w0 = *(const float4*)(Wt + (4 * kc + 0) * WROW + t4);
      float4 w1 = *(const float4*)(Wt + (4 * kc + 1) * WROW + t4);
      float4 w2 = *(const float4*)(Wt + (4 * kc + 2) * WROW + t4);
      float4 w3 = *(const float4*)(Wt + (4 * kc + 3) * WROW + t4);
      r.x = fmaf(a0, w0.x, r.x); r.y = fmaf(a0, w0.y, r.y);
      r.z = fmaf(a0, w0.z, r.z); r.w = fmaf(a0, w0.w, r.w);
      r.x = fmaf(a1, w1.x, r.x); r.y = fmaf(a1, w1.y, r.y);
      r.z = fmaf(a1, w1.z, r.z); r.w = fmaf(a1, w1.w, r.w);
      r.x = fmaf(a2, w2.x, r.x); r.y = fmaf(a2, w2.y, r.y);
      r.z = fmaf(a2, w2.z, r.z); r.w = fmaf(a2, w2.w, r.w);
      r.x = fmaf(a3, w3.x, r.x); r.y = fmaf(a3, w3.y, r.y);
      r.z = fmaf(a3, w3.z, r.z); r.w = fmaf(a3, w3.w, r.w);
    }
    r.x = fmaxf(r.x, 0.f); r.y = fmaxf(r.y, 0.f);
    r.z = fmaxf(r.z, 0.f); r.w = fmaxf(r.w, 0.f);

    if (POOL) {
      if (valid) {
        int gi = gid[n];
        atomicAdd(&lsum[gi * DIM + t4 + 0], r.x);
        atomicAdd(&lsum[gi * DIM + t4 + 1], r.y);
        atomicAdd(&lsum[gi * DIM + t4 + 2], r.z);
        atomicAdd(&lsum[gi * DIM + t4 + 3], r.w);
        if (idx == 0) atomicAdd(&lcnt[gi], 1.0f);
      }
    } else if (valid) {
      float sn = snorm[n];  // prescale for next layer
      float4 o = make_float4(r.x * sn, r.y * sn, r.z * sn, r.w * sn);
      *(float4*)(out + (size_t)n * DIM + t4) = o;
    }
  }

  if (POOL) {
    __syncthreads();
    for (int t = threadIdx.x; t < NG * DIM; t += blockDim.x) atomicAdd(&gsum[t], lsum[t]);
    if (threadIdx.x < NG) atomicAdd(&gcnt[threadIdx.x], lcnt[threadIdx.x]);
  }
}

// ---- head ----
__global__ void final_kernel(const float* __restrict__ gsum, const float* __restrict__ gcnt,
                             const float* __restrict__ Wp, const float* __restrict__ bp,
                             float* __restrict__ out) {
  int lane = threadIdx.x;  // 64
#pragma unroll
  for (int g = 0; g < NG; ++g) {
    float inv = 1.0f / fmaxf(gcnt[g], 1.0f);
    float hv = gsum[g * DIM + lane] * inv;
#pragma unroll
    for (int c = 0; c < 2; ++c) {
      float p = hv * Wp[lane * 2 + c];
      for (int off = 32; off; off >>= 1) p += __shfl_down(p, off, 64);
      if (lane == 0) out[g * 2 + c] = p + bp[c];
    }
  }
}

extern "C" void kernel_launch(void* const* d_in, const int* in_sizes, int n_in,
                              void* d_out, int out_size, void* d_ws, size_t ws_size,
                              hipStream_t stream) {
  const float* features = (const float*)d_in[0];
  const float* W1 = (const float*)d_in[1];
  const float* b1 = (const float*)d_in[2];
  const float* W2 = (const float*)d_in[3];
  const float* b2 = (const float*)d_in[4];
  const float* Wp = (const float*)d_in[5];
  const float* bp = (const float*)d_in[6];
  const int* esrc = (const int*)d_in[7];
  const int* edst = (const int*)d_in[8];
  const int* gid = (const int*)d_in[9];
  float* out = (float*)d_out;

  const int N = NN, E = NE;

  // workspace: zeroed region first
  int* outdeg = (int*)d_ws;            // N
  int* indeg = outdeg + N;             // N
  int* cnt = indeg + N;                // N
  float* gsum = (float*)(cnt + N);     // NG*DIM
  float* gcnt = gsum + NG * DIM;       // NG
  int* rp = (int*)(gcnt + NG);         // N
  int* bsum = rp + N;                  // 512
  int* boff = bsum + 512;              // 512
  int* col = boff + 512;               // E
  float* snorm = (float*)(col + E);    // N
  float* dnorm = snorm + N;            // N
  float* A = dnorm + N;                // (N+1)*DIM, row N is the zero row

  size_t zeroBytes = ((size_t)3 * N + NG * DIM + NG) * sizeof(int);
  hipMemsetAsync(d_ws, 0, zeroBytes, stream);
  hipMemsetAsync(A + (size_t)N * DIM, 0, DIM * sizeof(float), stream);  // zero row

  degree_kernel<<<2048, 256, 0, stream>>>(esrc, edst, outdeg, indeg, E);
  norm_kernel<<<(N + 255) / 256, 256, 0, stream>>>(outdeg, indeg, snorm, dnorm, N);

  scan1_kernel<<<NB, SCAN_BS, 0, stream>>>(indeg, rp, bsum, N);
  scan2_kernel<<<1, 512, 0, stream>>>(bsum, boff, NB);
  scan3_kernel<<<NB, SCAN_BS, 0, stream>>>(rp, boff, N);

  fill_kernel<<<2048, 256, 0, stream>>>(esrc, edst, rp, cnt, col, E);

  gconv_kernel<0, 0><<<2048, 256, 0, stream>>>(features, snorm, dnorm, rp, indeg, col,
                                               W1, b1, A, gid, gsum, gcnt, N);
  gconv_kernel<1, 1><<<2048, 256, 0, stream>>>(A, snorm, dnorm, rp, indeg, col,
                                               W2, b2, nullptr, gid, gsum, gcnt, N);

  final_kernel<<<1, 64, 0, stream>>>(gsum, gcnt, Wp, bp, out);
}